// Round 1
// baseline (258.843 us; speedup 1.0000x reference)
//
#include <hip/hip_runtime.h>

#define N_PTS 32768
#define BATCH 16
#define PIO2F 1.5707963705062866f

// ---------------- helpers ----------------
__device__ __forceinline__ float silu_f(float v) {
    // v * sigmoid(v) = v / (1 + exp(-v)); rcp approx is ~1e-7 rel, fine vs 2e-2 tol
    return v * __builtin_amdgcn_rcpf(1.0f + __expf(-v));
}

__device__ __forceinline__ float wave_sum(float v) {
    #pragma unroll
    for (int off = 1; off < 64; off <<= 1) v += __shfl_xor(v, off, 64);
    return v;
}

// ---------------- kernel 1: posenc (once per point, batch-invariant) ----------------
__global__ void posenc_kernel(const float* __restrict__ x, float* __restrict__ H0) {
    int p = blockIdx.x * 256 + threadIdx.x;
    float x0 = x[2 * p], x1 = x[2 * p + 1];
    float4 buf[16];
    float* d = (float*)buf;
    d[0] = x0; d[1] = x1;
    #pragma unroll
    for (int s = 0; s < 15; s++) {
        float sc = (float)(1 << s);
        float a0 = x0 * sc, a1 = x1 * sc;
        d[2 + 2 * s]  = sinf(a0);
        d[3 + 2 * s]  = sinf(a1);
        d[32 + 2 * s] = sinf(a0 + PIO2F);
        d[33 + 2 * s] = sinf(a1 + PIO2F);
    }
    d[62] = 0.f; d[63] = 0.f;
    float4* dst4 = (float4*)(H0 + (size_t)p * 64);
    #pragma unroll
    for (int j = 0; j < 16; j++) dst4[j] = buf[j];
}

// ---------------- kernel 2: hyper-weights wv (4 layers fused) ----------------
// block = 64 threads; grid = 4 layers * 16 b * 16 o = 1024
__global__ void wv_kernel(
    const float* __restrict__ latent,
    const float* __restrict__ pw0, const float* __restrict__ pb0,
    const float* __restrict__ lnw0, const float* __restrict__ lnb0,
    const float* __restrict__ pw1, const float* __restrict__ pb1,
    const float* __restrict__ lnw1, const float* __restrict__ lnb1,
    const float* __restrict__ pw2, const float* __restrict__ pb2,
    const float* __restrict__ lnw2, const float* __restrict__ lnb2,
    const float* __restrict__ pw3, const float* __restrict__ pb3,
    const float* __restrict__ lnw3, const float* __restrict__ lnb3,
    float* __restrict__ wvb) {
    int blk = blockIdx.x;
    int l = blk >> 8;
    int rest = blk & 255;
    int b = rest >> 4, o = rest & 15;
    int c = threadIdx.x;

    const float *pw, *pb, *lnw, *lnb;
    float* outp;
    int ch;
    switch (l) {
        case 0:  pw = pw0; pb = pb0; lnw = lnw0; lnb = lnb0; outp = wvb;                 ch = 62; break;
        case 1:  pw = pw1; pb = pb1; lnw = lnw1; lnb = lnb1; outp = wvb + 15872;         ch = 16; break;
        case 2:  pw = pw2; pb = pb2; lnw = lnw2; lnb = lnb2; outp = wvb + 15872 + 4096;  ch = 16; break;
        default: pw = pw3; pb = pb3; lnw = lnw3; lnb = lnb3; outp = wvb + 15872 + 8192;  ch = 16; break;
    }
    const float* lat = latent + ((size_t)(b * 64 + l * 16 + o)) * 64;  // uniform -> s_load
    float dot = 0.f;
    if (c < ch) {
        const float* pr = pw + ((size_t)(o * ch + c)) * 64;
        #pragma unroll
        for (int d0 = 0; d0 < 64; d0++) dot += lat[d0] * pr[d0];
    }
    float act = (c < ch) ? dot : 0.f;
    float mu = wave_sum(act) * (1.0f / ch);
    float diff = (c < ch) ? (dot - mu) : 0.f;
    float var = wave_sum(diff * diff) * (1.0f / ch);
    float norm = diff * rsqrtf(var + 1e-5f);
    if (c < ch) outp[(size_t)(b * 16 + o) * ch + c] = norm * lnw[c] + lnb[c] + pb[o * ch + c];
}

// ---------------- kernel 3: main per-point MLP ----------------
template <bool USE_H0>
__global__ __launch_bounds__(256) void main_kernel(
    const float* __restrict__ x, const float* __restrict__ H0,
    const float* __restrict__ wvb,
    const float* __restrict__ mb0, const float* __restrict__ mb1,
    const float* __restrict__ mb2, const float* __restrict__ mb3,
    const float* __restrict__ w1, const float* __restrict__ b1,
    const float* __restrict__ w2, const float* __restrict__ b2,
    const float* __restrict__ w3, const float* __restrict__ b3,
    float* __restrict__ out) {
    int b = blockIdx.x >> 7;
    int p = ((blockIdx.x & 127) << 8) | threadIdx.x;

    float h[62];
    if (USE_H0) {
        const float4* src = (const float4*)(H0 + (size_t)p * 64);
        #pragma unroll
        for (int j = 0; j < 15; j++) {
            float4 v = src[j];
            h[4 * j] = v.x; h[4 * j + 1] = v.y; h[4 * j + 2] = v.z; h[4 * j + 3] = v.w;
        }
        float4 v = src[15];
        h[60] = v.x; h[61] = v.y;
    } else {
        float x0 = x[2 * p], x1 = x[2 * p + 1];
        h[0] = x0; h[1] = x1;
        #pragma unroll
        for (int s = 0; s < 15; s++) {
            float sc = (float)(1 << s);
            float a0 = x0 * sc, a1 = x1 * sc;
            h[2 + 2 * s] = sinf(a0);
            h[3 + 2 * s] = sinf(a1);
            h[32 + 2 * s] = sinf(a0 + PIO2F);
            h[33 + 2 * s] = sinf(a1 + PIO2F);
        }
    }

    const float* wv0 = wvb + b * 992;                 // [16][62]
    const float* wv1 = wvb + 15872 + b * 256;         // [16][16]
    const float* wv2 = wvb + 15872 + 4096 + b * 256;
    const float* wv3 = wvb + 15872 + 8192 + b * 256;

    float ha[16], hb[16];
    // layer 0: 62 -> 16
    #pragma unroll
    for (int o = 0; o < 16; o++) {
        float acc = mb0[o];
        #pragma unroll
        for (int i = 0; i < 62; i++) acc += h[i] * wv0[o * 62 + i];
        ha[o] = silu_f(acc);
    }
    // layer 1: 16 -> 16
    #pragma unroll
    for (int o = 0; o < 16; o++) {
        float acc = mb1[o];
        #pragma unroll
        for (int i = 0; i < 16; i++) acc += ha[i] * wv1[o * 16 + i];
        hb[o] = silu_f(acc);
    }
    // layer 2: 16 -> 16
    #pragma unroll
    for (int o = 0; o < 16; o++) {
        float acc = mb2[o];
        #pragma unroll
        for (int i = 0; i < 16; i++) acc += hb[i] * wv2[o * 16 + i];
        ha[o] = silu_f(acc);
    }
    // layer 3: 16 -> 16
    #pragma unroll
    for (int o = 0; o < 16; o++) {
        float acc = mb3[o];
        #pragma unroll
        for (int i = 0; i < 16; i++) acc += ha[i] * wv3[o * 16 + i];
        hb[o] = silu_f(acc);
    }
    // w1: 16 -> 100 (h2 must be statically indexed -> full unroll)
    float h2[100];
    #pragma unroll
    for (int i = 0; i < 100; i++) {
        float acc = b1[i];
        #pragma unroll
        for (int k = 0; k < 16; k++) acc += hb[k] * w1[i * 16 + k];
        h2[i] = silu_f(acc);
    }
    // w2 (100x100) fused with w3 (1x100): each h3[o] is a scalar, consumed immediately
    float outv = b3[0];
    for (int o = 0; o < 100; o++) {  // o uniform loop var -> s_load weights
        const float* wr = w2 + o * 100;
        float a0 = b2[o], a1 = 0.f, a2 = 0.f, a3 = 0.f;
        #pragma unroll
        for (int j = 0; j < 100; j += 4) {
            a0 += h2[j]     * wr[j];
            a1 += h2[j + 1] * wr[j + 1];
            a2 += h2[j + 2] * wr[j + 2];
            a3 += h2[j + 3] * wr[j + 3];
        }
        outv += silu_f((a0 + a1) + (a2 + a3)) * w3[o];
    }
    out[(size_t)b * N_PTS + p] = outv;
}

// ---------------- launcher ----------------
extern "C" void kernel_launch(void* const* d_in, const int* in_sizes, int n_in,
                              void* d_out, int out_size, void* d_ws, size_t ws_size,
                              hipStream_t stream) {
    const float* x = (const float*)d_in[0];
    const float* latent = (const float*)d_in[1];
    const float *pw[4], *pb[4], *lnw[4], *lnb[4], *mb[4];
    for (int l = 0; l < 4; l++) {
        pw[l]  = (const float*)d_in[2 + 5 * l];
        pb[l]  = (const float*)d_in[3 + 5 * l];
        lnw[l] = (const float*)d_in[4 + 5 * l];
        lnb[l] = (const float*)d_in[5 + 5 * l];
        mb[l]  = (const float*)d_in[6 + 5 * l];
    }
    const float* w1 = (const float*)d_in[22];
    const float* b1 = (const float*)d_in[23];
    const float* w2 = (const float*)d_in[24];
    const float* b2 = (const float*)d_in[25];
    const float* w3 = (const float*)d_in[26];
    const float* b3 = (const float*)d_in[27];

    float* wsf = (float*)d_ws;
    const size_t H0_FLOATS = (size_t)N_PTS * 64;       // 2,097,152 floats (8 MB)
    const size_t WV_FLOATS = 15872 + 3 * 4096;         // 28,160 floats
    bool big = ws_size >= (H0_FLOATS + WV_FLOATS) * sizeof(float);

    float* H0  = big ? wsf : nullptr;
    float* wvb = big ? (wsf + H0_FLOATS) : wsf;

    if (big) posenc_kernel<<<128, 256, 0, stream>>>(x, H0);
    wv_kernel<<<1024, 64, 0, stream>>>(latent,
        pw[0], pb[0], lnw[0], lnb[0],
        pw[1], pb[1], lnw[1], lnb[1],
        pw[2], pb[2], lnw[2], lnb[2],
        pw[3], pb[3], lnw[3], lnb[3],
        wvb);

    dim3 grid(BATCH * (N_PTS / 256));
    if (big) {
        main_kernel<true><<<grid, 256, 0, stream>>>(x, H0, wvb,
            mb[0], mb[1], mb[2], mb[3], w1, b1, w2, b2, w3, b3, (float*)d_out);
    } else {
        main_kernel<false><<<grid, 256, 0, stream>>>(x, H0, wvb,
            mb[0], mb[1], mb[2], mb[3], w1, b1, w2, b2, w3, b3, (float*)d_out);
    }
}